// Round 16
// baseline (2207.187 us; speedup 1.0000x reference)
//
#include <hip/hip_runtime.h>

// MatchLSTM forward pipeline for MI355X.
// R16 = R15 (gemm f16 / match R14 / ptr unchanged) + enc_k rebalanced:
// Whh pairs 0..55 in 14 pinned uint4 regs (76 live words <= the allocator's
// fixed 84 target), pairs 56..75 in 48 KB LDS (was 86.4 KB stream/step);
// cell on 150 threads (halves the serial transcendental chain).

typedef _Float16 f16;
typedef f16 f16x2 __attribute__((ext_vector_type(2)));
typedef unsigned int u32;
typedef unsigned short u16;

constexpr int cLP = 400, cLQ = 50, cB = 32, cH = 150, cG = 600;

__device__ __forceinline__ float exp2_(float x){
#if __has_builtin(__builtin_amdgcn_exp2f)
  return __builtin_amdgcn_exp2f(x);
#else
  return exp2f(x);
#endif
}
__device__ __forceinline__ float rcp_(float x){
#if __has_builtin(__builtin_amdgcn_rcpf)
  return __builtin_amdgcn_rcpf(x);
#else
  return 1.0f / x;
#endif
}
__device__ __forceinline__ float sigm(float x){ return rcp_(1.f + exp2_(-1.44269504f * x)); }
__device__ __forceinline__ float tanh_(float x){ return 1.f - 2.f * rcp_(1.f + exp2_(2.88539008f * x)); }

union U2 { u32 u; f16x2 h; };

__device__ __forceinline__ float fdot2_(u32 a, u32 b, float c){
  U2 ua, ub; ua.u = a; ub.u = b;
#if __has_builtin(__builtin_amdgcn_fdot2)
  return __builtin_amdgcn_fdot2(ua.h, ub.h, c, false);
#else
  return c + (float)ua.h[0] * (float)ub.h[0] + (float)ua.h[1] * (float)ub.h[1];
#endif
}
__device__ __forceinline__ u32 pack2(float x, float y){
  U2 p; p.h[0] = (f16)x; p.h[1] = (f16)y; return p.u;
}
__device__ __forceinline__ float2 unp2(u32 v){
  U2 p; p.u = v; return make_float2((float)p.h[0], (float)p.h[1]);
}

// load 4 f16x2 pairs (8 floats) from a weight row at float offset 8*i
__device__ __forceinline__ uint4 ldw4(const float* __restrict__ wr, int i){
  uint4 r;
  r.x = pack2(wr[8*i+0], wr[8*i+1]);
  r.y = pack2(wr[8*i+2], wr[8*i+3]);
  r.z = pack2(wr[8*i+4], wr[8*i+5]);
  r.w = pack2(wr[8*i+6], wr[8*i+7]);
  return r;
}

// opaque barrier: values become asm outputs -> cannot be rematerialized
#define PIN4(v) asm volatile("" : "+v"(v.x), "+v"(v.y), "+v"(v.z), "+v"(v.w));
#define PIN4W(i) PIN4(w##i)
#define PIN4Q(i) PIN4(q##i)

#define REP10(M) M(0) M(1) M(2) M(3) M(4) M(5) M(6) M(7) M(8) M(9)
#define REP14(M) REP10(M) M(10) M(11) M(12) M(13)
#define REP6(M) M(0) M(1) M(2) M(3) M(4) M(5)

// ---------------------------------------------------------------------------
// f16-fdot2 GEMM (R15, unchanged).
// ---------------------------------------------------------------------------
__global__ __launch_bounds__(256)
void gemm_k(const float* __restrict__ A, const int* __restrict__ ids,
            const float* __restrict__ emb,
            const float* __restrict__ W, int ldw, const float* __restrict__ bias,
            float* __restrict__ Cf, f16* __restrict__ Ch,
            int M, int N, int K)
{
  __shared__ __align__(16) u32 As2[8][64];
  __shared__ __align__(16) u32 Wt2[8][64];
  __shared__ int sids[64];
  int tid = threadIdx.x;
  int n0 = blockIdx.x * 64;
  int m0 = blockIdx.y * 64;
  int tx = tid & 15, ty = tid >> 4;
  if (ids){ if (tid < 64) sids[tid] = ids[m0 + tid]; }
  __syncthreads();

  float acc[4][4] = {};
  int sm = tid >> 2;
  int kq = tid & 3;
  const float* arow = ids ? (emb + (size_t)sids[sm] * K)
                          : (A   + (size_t)(m0 + sm) * K);
  const float* wrow = W + (size_t)(n0 + sm) * ldw;
  bool nok = (n0 + sm) < N;

  for (int k0 = 0; k0 < K; k0 += 16){
    {
      int kb = k0 + 4 * kq;
      float a0 = (kb     < K) ? arow[kb]     : 0.f;
      float a1 = (kb + 1 < K) ? arow[kb + 1] : 0.f;
      float a2 = (kb + 2 < K) ? arow[kb + 2] : 0.f;
      float a3 = (kb + 3 < K) ? arow[kb + 3] : 0.f;
      As2[2 * kq][sm]     = pack2(a0, a1);
      As2[2 * kq + 1][sm] = pack2(a2, a3);
      float w0 = (nok && kb     < K) ? wrow[kb]     : 0.f;
      float w1 = (nok && kb + 1 < K) ? wrow[kb + 1] : 0.f;
      float w2 = (nok && kb + 2 < K) ? wrow[kb + 2] : 0.f;
      float w3 = (nok && kb + 3 < K) ? wrow[kb + 3] : 0.f;
      Wt2[2 * kq][sm]     = pack2(w0, w1);
      Wt2[2 * kq + 1][sm] = pack2(w2, w3);
    }
    __syncthreads();
    #pragma unroll
    for (int p = 0; p < 8; p++){
      uint4 av = *(const uint4*)&As2[p][ty << 2];
      uint4 wv = *(const uint4*)&Wt2[p][tx << 2];
      u32 a[4] = {av.x, av.y, av.z, av.w};
      u32 w[4] = {wv.x, wv.y, wv.z, wv.w};
      #pragma unroll
      for (int i = 0; i < 4; i++)
        #pragma unroll
        for (int j = 0; j < 4; j++)
          acc[i][j] = fdot2_(a[i], w[j], acc[i][j]);
    }
    __syncthreads();
  }
  float bj[4];
  #pragma unroll
  for (int j = 0; j < 4; j++){
    int n = n0 + (tx << 2) + j;
    bj[j] = (bias && n < N) ? bias[n] : 0.f;
  }
  #pragma unroll
  for (int i = 0; i < 4; i++){
    int m = m0 + (ty << 2) + i;
    #pragma unroll
    for (int j = 0; j < 4; j++){
      int n = n0 + (tx << 2) + j;
      if (n < N){
        size_t ci = (size_t)m * N + n;
        float v = acc[i][j] + bj[j];
        if (Ch) Ch[ci] = (f16)v; else Cf[ci] = v;
      }
    }
  }
}

// ---------------------------------------------------------------------------
// Encoder LSTM. Whh pairs 0..55 in 14 pinned uint4 regs; pairs 56..75 in
// 48 KB LDS. Cell on 150 threads. Same 2-barrier step.
// ---------------------------------------------------------------------------
__attribute__((amdgpu_waves_per_eu(1, 3)))
__global__ __launch_bounds__(640)
void enc_k(const float* __restrict__ XGp, const float* __restrict__ XGq,
           const float* __restrict__ Whh,
           const int* __restrict__ plens, const int* __restrict__ qlens,
           float* __restrict__ Hp, float* __restrict__ Hq)
{
  int wg = blockIdx.x;
  bool isq = wg >= cB;
  int b = wg & (cB - 1);
  const float* XG = isq ? XGq : XGp;
  float* Hout = isq ? Hq : Hp;
  int T   = isq ? cLQ : cLP;
  int len = (isq ? qlens : plens)[b];
  int tid = threadIdx.x;

  __shared__ __align__(16) u32 WhhL4[5 * 600 * 4];   // pairs 56..75 (48 KB)
  __shared__ float c[cH], gl[cG];
  __shared__ __align__(16) f16 hsf[160];

#define DECLW(i) uint4 w##i;
  REP14(DECLW)
#undef DECLW
  {
    const float* wr = Whh + (size_t)(tid < cG ? tid : 0) * cH;
#define LOADW(i) w##i = ldw4(wr, i);
    REP14(LOADW)
#undef LOADW
    REP14(PIN4W)
  }
  for (int idx = tid; idx < 5 * 600; idx += 640){
    int g = idx / 600, r = idx % 600;
    const float* wrow = Whh + (size_t)r * cH + 112;
    uint4 v;
    if (g < 4) v = ldw4(wrow, g);
    else {
      v.x = pack2(wrow[32], wrow[33]);   // floats 144,145
      v.y = pack2(wrow[34], wrow[35]);   // 146,147
      v.z = pack2(wrow[36], wrow[37]);   // 148,149
      v.w = 0;
    }
    *(uint4*)&WhhL4[idx * 4] = v;
  }
  if (tid < cH) c[tid] = 0.f;
  if (tid < 160) hsf[tid] = (f16)0.f;
  __syncthreads();

  float xgCur = 0.f;
  if (tid < cG) xgCur = XG[(size_t)b * cG + tid];

  for (int t = 0; t < T; t++){
    int tn = (t + 1 < T) ? t + 1 : t;
    float xgN = 0.f;
    if (tid < cG) xgN = XG[((size_t)tn * cB + b) * cG + tid];

    if (tid < cG){
      float aA = 0.f, aB = 0.f, aC = 0.f, aD = 0.f;
#define DOTW(i) { uint4 hq = *(const uint4*)&hsf[8*(i)]; \
      aA = fdot2_(hq.x, w##i.x, aA); aB = fdot2_(hq.y, w##i.y, aB); \
      aC = fdot2_(hq.z, w##i.z, aC); aD = fdot2_(hq.w, w##i.w, aD); }
      REP14(DOTW)
#undef DOTW
      #pragma unroll
      for (int g = 0; g < 5; g++){
        uint4 hq = *(const uint4*)&hsf[112 + 8 * g];
        uint4 wv = *(const uint4*)&WhhL4[(g * 600 + tid) * 4];
        aA = fdot2_(hq.x, wv.x, aA);
        aB = fdot2_(hq.y, wv.y, aB);
        aC = fdot2_(hq.z, wv.z, aC);
        aD = fdot2_(hq.w, wv.w, aD);
      }
      gl[tid] = xgCur + ((aA + aB) + (aC + aD));
    }
    __syncthreads();
    if (tid < cH){
      float ig = sigm(gl[tid]);
      float fg = sigm(gl[cH + tid]);
      float gg = tanh_(gl[2 * cH + tid]);
      float og = sigm(gl[3 * cH + tid]);
      float c2 = fg * c[tid] + ig * gg;     // unmasked recurrence
      float hh = og * tanh_(c2);
      c[tid] = c2;
      hsf[tid] = (f16)hh;
      float mk = (t < len) ? 1.f : 0.f;
      Hout[((size_t)t * cB + b) * cH + tid] = hh * mk;
    }
    __syncthreads();
    xgCur = xgN;
  }
}

// ---------------------------------------------------------------------------
// Match-LSTM, fwd + bwd (R14 structure, unchanged).
// ---------------------------------------------------------------------------
__attribute__((amdgpu_waves_per_eu(1, 3)))
__global__ __launch_bounds__(640)
void match_k(const f16* __restrict__ XAf, const f16* __restrict__ XAb,
             const f16* __restrict__ QWf, const f16* __restrict__ QWb,
             const float* __restrict__ aq, const float* __restrict__ pp,
             const float* __restrict__ mfWhh, const float* __restrict__ mbWhh,
             const float* __restrict__ mfb, const float* __restrict__ mbb,
             const float* __restrict__ Wr, const float* __restrict__ wa,
             const int* __restrict__ plens, float* __restrict__ Hr)
{
  constexpr int NPAD = 160;
  int wg = blockIdx.x;
  int dir = wg >> 5;
  int b = wg & 31;
  const f16* XA = dir ? XAb : XAf;
  const f16* QW = dir ? QWb : QWf;
  const float* Whh = dir ? mbWhh : mfWhh;
  const float* bm  = dir ? mbb   : mfb;
  int len = plens[b];
  int tid = threadIdx.x;

  __shared__ __align__(16) u32 WhhL4[9 * 600 * 4];   // 86.4 KB
  __shared__ __align__(16) u32 WrT4[20 * 150 * 4];   // 48 KB (row 19 = zeros)
  __shared__ __align__(16) u32 aq3[cLQ * 96];        // 19.2 KB
  __shared__ float gl[cG];
  __shared__ __align__(16) float sc[NPAD];
  __shared__ __align__(16) float waS[NPAD];
  __shared__ float c[cH];
  __shared__ __align__(16) f16 hsf[160];             // h as raw f16
  __shared__ float loge[64];
  __shared__ __align__(16) u32 alpha2[28];

  // ---- one-time loads ----
#define DECLW(i) uint4 w##i;
  REP10(DECLW)
#undef DECLW
  float bk = 0.f;
  {
    const float* wr = Whh + (size_t)(tid < cG ? tid : 0) * cH;
#define LOADW(i) w##i = ldw4(wr, i);
    REP10(LOADW)
#undef LOADW
    REP10(PIN4W)
    if (tid < cG) bk = bm[tid];
  }
#define DECLQ(i) uint4 q##i;
  REP6(DECLQ)
#undef DECLQ
  u32 q24s;
  {
    const u16* QWu = (const u16*)QW;
    int row = (tid < cG) ? tid : 0;
#define QP(p) ((u32)QWu[((size_t)(2*(p)) * cB + b) * cG + row] | \
               ((u32)QWu[((size_t)(2*(p)+1) * cB + b) * cG + row] << 16))
#define LOADQ(i) q##i.x = QP(4*(i)+0); q##i.y = QP(4*(i)+1); \
                 q##i.z = QP(4*(i)+2); q##i.w = QP(4*(i)+3);
    LOADQ(0) LOADQ(1) LOADQ(2) LOADQ(3) LOADQ(4) LOADQ(5)
    q24s = QP(24);
#undef LOADQ
#undef QP
    REP6(PIN4Q)
    asm volatile("" : "+v"(q24s));
  }
  for (int idx = tid; idx < 9 * 600; idx += 640){
    int p4 = idx / 600, r = idx % 600;
    const float* wrow = Whh + (size_t)r * cH + 80;
    uint4 v;
    if (p4 < 8) v = ldw4(wrow, p4);
    else {
      v.x = pack2(wrow[64], wrow[65]);
      v.y = pack2(wrow[66], wrow[67]);
      v.z = pack2(wrow[68], wrow[69]);
      v.w = 0;
    }
    *(uint4*)&WhhL4[idx * 4] = v;
  }
  for (int idx = tid; idx < 20 * 150; idx += 640){
    int i = idx / 150, j = idx % 150;
    const float* wrow = Wr + (size_t)j * cH;
    uint4 v = {0, 0, 0, 0};
    if (i < 18) v = ldw4(wrow, i);
    else if (i == 18){
      v.x = pack2(wrow[144], wrow[145]);
      v.y = pack2(wrow[146], wrow[147]);
      v.z = pack2(wrow[148], wrow[149]);
      v.w = 0;
    }
    *(uint4*)&WrT4[idx * 4] = v;
  }
  for (int idx = tid; idx < cLQ * 96; idx += 640){
    int l = idx / 96, s = idx % 96;
    int ch = s / 12, t = s % 12;
    u32 v = 0;
    if (t < 10){
      int p = ch * 10 + t;
      if (p < 75){
        const float* ap = aq + ((size_t)l * cB + b) * cH;
        v = pack2(ap[2 * p], ap[2 * p + 1]);
      }
    }
    aq3[idx] = v;
  }
  for (int i = tid; i < NPAD; i += 640) waS[i] = (i < cH) ? wa[i] : 0.f;
  if (tid < cH) c[tid] = 0.f;
  if (tid < 160) hsf[tid] = (f16)0.f;
  if (tid >= cH && tid < NPAD) sc[tid] = 0.f;
  if (tid >= 25 && tid < 28) alpha2[tid] = 0;
  __syncthreads();

  // prologue prefetch for step 0
  f16 xaCurH = (f16)0.f, xaNxtH = (f16)0.f;
  float ppCur = 0.f, ppNxt = 0.f;
  {
    int t0 = dir ? (cLP - 1) : 0;
    if (tid < cG) xaCurH = XA[((size_t)t0 * cB + b) * cG + tid];
    if (tid < cG && (tid & 3) == 0)
      ppCur = pp[((size_t)t0 * cB + b) * cH + (tid >> 2)];
  }

  for (int s = 0; s < cLP; s++){
    int tt = dir ? (cLP - 1 - s) : s;
    float mk = (tt < len) ? 1.f : 0.f;

    // prefetch step s+1 (consumed next iteration)
    {
      int sn = (s + 1 < cLP) ? s + 1 : s;
      int tn = dir ? (cLP - 1 - sn) : sn;
      if (tid < cG) xaNxtH = XA[((size_t)tn * cB + b) * cG + tid];
      if (tid < cG && (tid & 3) == 0)
        ppNxt = pp[((size_t)tn * cB + b) * cH + (tid >> 2)];
    }

    // P_A: sc = h@Wr^T + pp[tt]; 4 lanes per column, shfl reduce.
    if (tid < cG){
      int q = tid & 3, j = tid >> 2;
      float sA = 0.f, sB = 0.f, sC = 0.f, sD = 0.f;
      #pragma unroll
      for (int i0 = 0; i0 < 5; i0++){
        int i = 5 * q + i0;               // q=3,i0=4 -> row 19 (zeros)
        uint4 hq = *(const uint4*)&hsf[8 * i];
        uint4 wv = *(const uint4*)&WrT4[(i * 150 + j) * 4];
        sA = fdot2_(hq.x, wv.x, sA);
        sB = fdot2_(hq.y, wv.y, sB);
        sC = fdot2_(hq.z, wv.z, sC);
        sD = fdot2_(hq.w, wv.w, sD);
      }
      float v = (sA + sB) + (sC + sD);
      v += __shfl_xor(v, 1);
      v += __shfl_xor(v, 2);
      if (q == 0) sc[j] = v + ppCur;
    }
    __syncthreads();

    // P_B: gates_pre (tid<600, WhhL4 stream, kept in VGPR) + logits (tid<400)
    float gpre = 0.f;
    if (tid < cG){
      float aA = 0.f, aB = 0.f, aC = 0.f, aD = 0.f;
#define DOTW(i) { uint4 hq = *(const uint4*)&hsf[8*(i)]; \
      aA = fdot2_(hq.x, w##i.x, aA); aB = fdot2_(hq.y, w##i.y, aB); \
      aC = fdot2_(hq.z, w##i.z, aC); aD = fdot2_(hq.w, w##i.w, aD); }
      REP10(DOTW)
#undef DOTW
      #pragma unroll
      for (int p4 = 0; p4 < 9; p4++){
        uint4 hq = *(const uint4*)&hsf[80 + 8 * p4];
        uint4 wv = *(const uint4*)&WhhL4[(p4 * 600 + tid) * 4];
        aA = fdot2_(hq.x, wv.x, aA);
        aB = fdot2_(hq.y, wv.y, aB);
        aC = fdot2_(hq.z, wv.z, aC);
        aD = fdot2_(hq.w, wv.w, aD);
      }
      gpre = bk + ((aA + aB) + (aC + aD));
    }
    if (tid < 400){
      int l = tid >> 3, q8 = tid & 7;
      const u32* ab = aq3 + l * 96 + q8 * 12;
      uint4 A0 = *(const uint4*)(ab);
      uint4 A1 = *(const uint4*)(ab + 4);
      uint2 A2 = *(const uint2*)(ab + 8);
      u32 aqp[10] = {A0.x, A0.y, A0.z, A0.w, A1.x, A1.y, A1.z, A1.w, A2.x, A2.y};
      const float4* scv = (const float4*)(sc  + 20 * q8);
      const float4* wav = (const float4*)(waS + 20 * q8);
      float p0 = 0.f, p1 = 0.f;
      #pragma unroll
      for (int i = 0; i < 5; i++){
        float4 sv = scv[i];
        float4 wv = wav[i];
        float2 a0 = unp2(aqp[2 * i]);
        float2 a1 = unp2(aqp[2 * i + 1]);
        p0 += wv.x * rcp_(1.f + exp2_(2.88539008f * (a0.x + sv.x)));
        p1 += wv.y * rcp_(1.f + exp2_(2.88539008f * (a0.y + sv.y)));
        p0 += wv.z * rcp_(1.f + exp2_(2.88539008f * (a1.x + sv.z)));
        p1 += wv.w * rcp_(1.f + exp2_(2.88539008f * (a1.y + sv.w)));
      }
      float part = p0 + p1;
      part += __shfl_xor(part, 1);
      part += __shfl_xor(part, 2);
      part += __shfl_xor(part, 4);
      if (q8 == 0) loge[l] = part;
    }
    __syncthreads();

    // P_C: softmax over 50 on wave 0, f16-packed alpha pairs
    if (tid < 64){
      float lg = (tid < cLQ) ? (-2.f * loge[tid]) : -1e30f;
      float mx = lg;
      #pragma unroll
      for (int off = 32; off; off >>= 1) mx = fmaxf(mx, __shfl_xor(mx, off));
      float e = (tid < cLQ) ? exp2_((lg - mx) * 1.44269504f) : 0.f;
      float sum = e;
      #pragma unroll
      for (int off = 32; off; off >>= 1) sum += __shfl_xor(sum, off);
      float al = e * rcp_(sum);
      float alhi = __shfl_down(al, 1);
      if (tid < cLQ && !(tid & 1)) alpha2[tid >> 1] = pack2(al, alhi);
    }
    __syncthreads();

    // P_D: gl = gpre + mk*(XA + alpha@QW)
    if (tid < cG){
      float qA = 0.f, qB = 0.f;
#define DOTQ(i) { uint4 a4 = *(const uint4*)&alpha2[4*(i)]; \
      qA = fdot2_(a4.x, q##i.x, qA); qB = fdot2_(a4.y, q##i.y, qB); \
      qA = fdot2_(a4.z, q##i.z, qA); qB = fdot2_(a4.w, q##i.w, qB); }
      REP6(DOTQ)
#undef DOTQ
      qA = fdot2_(alpha2[24], q24s, qA);
      gl[tid] = gpre + mk * ((float)xaCurH + (qA + qB));
    }
    __syncthreads();

    // P_E: cell on 150 threads; h2,c2 masked inside recurrence.
    if (tid < cH){
      float ig = sigm(gl[tid]);
      float fg = sigm(gl[cH + tid]);
      float gg = tanh_(gl[2 * cH + tid]);
      float og = sigm(gl[3 * cH + tid]);
      float c2 = (fg * c[tid] + ig * gg) * mk;
      float hh = og * tanh_(c2) * mk;
      c[tid] = c2;
      hsf[tid] = (f16)hh;
      Hr[((size_t)tt * cB + b) * (2 * cH) + dir * cH + tid] = hh;
    }
    __syncthreads();

    xaCurH = xaNxtH;
    ppCur  = ppNxt;
  }
}

// ---------------------------------------------------------------------------
// Answer pointer: 32 WGs (one per batch), 2 sequential iterations.
// ---------------------------------------------------------------------------
__global__ __launch_bounds__(640)
void ptr_k(const float* __restrict__ am, const float* __restrict__ Hr,
           const float* __restrict__ Wa, const float* __restrict__ baa,
           const float* __restrict__ wb,
           const float* __restrict__ apWih, const float* __restrict__ apWhh,
             const float* __restrict__ apb, float* __restrict__ out)
{
  int b = blockIdx.x, tid = threadIdx.x;
  __shared__ float ha[cH], ca[cH], haWa[160], wbs[160];
  __shared__ float beta[cLP], wHr[2 * cH], gl[cG], red[20];
  if (tid < cH){ ha[tid] = 0.f; ca[tid] = 0.f; }
  if (tid < 160) wbs[tid] = (tid < cH) ? wb[tid] : 0.f;
  __syncthreads();

  for (int it = 0; it < 2; ++it){
    if (tid < cH){
      float acc = baa[tid];
      const float* wr = Wa + (size_t)tid * cH;
      for (int i = 0; i < cH; i++) acc += ha[i] * wr[i];
      haWa[tid] = acc;
    } else if (tid < 160) haWa[tid] = 0.f;
    __syncthreads();

    {
      int tt = tid >> 4;
      int jq = tid & 15;
      for (int t0 = 0; t0 < cLP; t0 += 40){
        int t = t0 + tt;
        float part = 0.f;
        const float* amr = am + ((size_t)t * cB + b) * cH;
        #pragma unroll
        for (int i = 0; i < 10; i++){
          int j = jq * 10 + i;
          if (j < cH){
            float F = tanh_(amr[j] + haWa[j]);
            part += wbs[j] * F;
          }
        }
        part += __shfl_xor(part, 1);
        part += __shfl_xor(part, 2);
        part += __shfl_xor(part, 4);
        part += __shfl_xor(part, 8);
        if (jq == 0) beta[t] = part;
      }
    }
    __syncthreads();

    float x = (tid < cLP) ? beta[tid] : -1e30f;
    float mx = x;
    #pragma unroll
    for (int off = 32; off; off >>= 1) mx = fmaxf(mx, __shfl_xor(mx, off));
    if ((tid & 63) == 0) red[tid >> 6] = mx;
    __syncthreads();
    if (tid == 0){
      float m2 = red[0];
      for (int w = 1; w < 10; w++) m2 = fmaxf(m2, red[w]);
      red[16] = m2;
    }
    __syncthreads();
    mx = red[16];
    float e = (tid < cLP) ? exp2_((x - mx) * 1.44269504f) : 0.f;
    float sm = e;
    #pragma unroll
    for (int off = 32; off; off >>= 1) sm += __shfl_xor(sm, off);
    if ((tid & 63) == 0) red[tid >> 6] = sm;
    __syncthreads();
    if (tid == 0){
      float s2 = 0.f;
      for (int w = 0; w < 10; w++) s2 += red[w];
      red[17] = s2;
    }
    __syncthreads();
    float bsum = red[17];
    if (tid < cLP){
      float bt = e * rcp_(bsum);
      beta[tid] = bt;
      out[(size_t)it * cLP * cB + (size_t)tid * cB + b] = bt;
    }
    __syncthreads();

    if (tid < 2 * cH){
      float acc = 0.f;
      for (int t = 0; t < cLP; t++)
        acc += beta[t] * Hr[((size_t)t * cB + b) * (2 * cH) + tid];
      wHr[tid] = acc;
    }
    __syncthreads();

    if (tid < cG){
      float acc = apb[tid];
      const float* r1 = apWih + (size_t)tid * (2 * cH);
      for (int i = 0; i < 2 * cH; i++) acc += wHr[i] * r1[i];
      const float* r2 = apWhh + (size_t)tid * cH;
      for (int i = 0; i < cH; i++) acc += ha[i] * r2[i];
      gl[tid] = acc;
    }
    __syncthreads();
    if (tid < cH){
      float ig = sigm(gl[tid]);
      float fg = sigm(gl[cH + tid]);
      float gg = tanh_(gl[2 * cH + tid]);
      float og = sigm(gl[3 * cH + tid]);
      float c2 = fg * ca[tid] + ig * gg;
      ca[tid] = c2;
      ha[tid] = og * tanh_(c2);
    }
    __syncthreads();
  }
}

// ---------------------------------------------------------------------------
extern "C" void kernel_launch(void* const* d_in, const int* in_sizes, int n_in,
                              void* d_out, int out_size, void* d_ws, size_t ws_size,
                              hipStream_t stream)
{
  (void)in_sizes; (void)n_in; (void)out_size; (void)ws_size;
  const int*   p_ids = (const int*)d_in[0];
  const int*   q_ids = (const int*)d_in[1];
  const int*   plens = (const int*)d_in[2];
  const int*   qlens = (const int*)d_in[3];
  const float* emb   = (const float*)d_in[4];
  const float* pWih  = (const float*)d_in[5];
  const float* pWhh  = (const float*)d_in[6];
  const float* pb    = (const float*)d_in[7];
  const float* Wq    = (const float*)d_in[8];
  const float* Wp    = (const float*)d_in[9];
  const float* bp    = (const float*)d_in[10];
  const float* Wr    = (const float*)d_in[11];
  const float* wa    = (const float*)d_in[12];
  const float* mfWih = (const float*)d_in[14];
  const float* mfWhh = (const float*)d_in[15];
  const float* mfb   = (const float*)d_in[16];
  const float* mbWih = (const float*)d_in[17];
  const float* mbWhh = (const float*)d_in[18];
  const float* mbb   = (const float*)d_in[19];
  const float* Vm    = (const float*)d_in[20];
  const float* Waa   = (const float*)d_in[21];
  const float* baa   = (const float*)d_in[22];
  const float* wb    = (const float*)d_in[23];
  const float* apWih = (const float*)d_in[25];
  const float* apWhh = (const float*)d_in[26];
  const float* apb   = (const float*)d_in[27];
  float* out = (float*)d_out;

  // workspace layout (floats); total 22,560,000 f = 90.24 MB
  float* ws  = (float*)d_ws;
  float* XGp = ws;                       // [400*32][600] f32 (later aliased XAf)
  float* XGq = ws + 7680000;             // [50*32][600]  f32 (later aliased QW)
  f16*   XAb = (f16*)(ws + 8640000);     // [400*32][600] f16
  float* Hp  = ws + 12480000;            // [400*32][150]
  float* Hq  = ws + 14400000;            // [50*32][150]
  float* aqb = ws + 14640000;            // [50*32][150]
  float* ppb = ws + 14880000;            // [400*32][150]
  float* Hr  = ws + 16800000;            // [400*32][300]
  float* am  = ws + 20640000;            // [400*32][150]
  f16*   XAf = (f16*)XGp;                // alias: XGp dead after enc_k
  f16*   QWf = (f16*)XGq;                // alias: XGq dead after enc_k
  f16*   QWb = QWf + (size_t)1600 * 600;

  dim3 blk(256);
  gemm_k<<<dim3(10,200), blk, 0, stream>>>(nullptr, p_ids, emb, pWih, 300, pb,
                                           XGp, nullptr, 12800, 600, 300);
  gemm_k<<<dim3(10, 25), blk, 0, stream>>>(nullptr, q_ids, emb, pWih, 300, pb,
                                           XGq, nullptr, 1600, 600, 300);
  enc_k<<<64, 640, 0, stream>>>(XGp, XGq, pWhh, plens, qlens, Hp, Hq);
  gemm_k<<<dim3(3,200), blk, 0, stream>>>(Hp, nullptr, nullptr, Wp, 150, bp,
                                          ppb, nullptr, 12800, 150, 150);
  gemm_k<<<dim3(3, 25), blk, 0, stream>>>(Hq, nullptr, nullptr, Wq, 150, nullptr,
                                          aqb, nullptr, 1600, 150, 150);
  gemm_k<<<dim3(10,200), blk, 0, stream>>>(Hp, nullptr, nullptr, mfWih, 300, nullptr,
                                           nullptr, XAf, 12800, 600, 150);
  gemm_k<<<dim3(10,200), blk, 0, stream>>>(Hp, nullptr, nullptr, mbWih, 300, nullptr,
                                           nullptr, XAb, 12800, 600, 150);
  gemm_k<<<dim3(10, 25), blk, 0, stream>>>(Hq, nullptr, nullptr, mfWih + 150, 300, nullptr,
                                           nullptr, QWf, 1600, 600, 150);
  gemm_k<<<dim3(10, 25), blk, 0, stream>>>(Hq, nullptr, nullptr, mbWih + 150, 300, nullptr,
                                           nullptr, QWb, 1600, 600, 150);
  match_k<<<64, 640, 0, stream>>>(XAf, XAb, QWf, QWb, aqb, ppb, mfWhh, mbWhh,
                                  mfb, mbb, Wr, wa, plens, Hr);
  gemm_k<<<dim3(3,200), blk, 0, stream>>>(Hr, nullptr, nullptr, Vm, 300, nullptr,
                                          am, nullptr, 12800, 150, 300);
  ptr_k<<<32, 640, 0, stream>>>(am, Hr, Waa, baa, wb, apWih, apWhh, apb, out);
}

// Round 17
// 2172.640 us; speedup vs baseline: 1.0159x; 1.0159x over previous
//
#include <hip/hip_runtime.h>

// MatchLSTM forward pipeline for MI355X.
// R17 = R15 exact revert (best measured: 2173 us). R16's enc rebalance was
// slightly negative (register budget collision at the allocator's fixed 84
// target). Final configuration: f16-fdot2 GEMM + R12/R14 match_k (5-phase,
// fused gates_pre+logits, reg/LDS-split weights) + R11 enc_k + ptr_k.

typedef _Float16 f16;
typedef f16 f16x2 __attribute__((ext_vector_type(2)));
typedef unsigned int u32;
typedef unsigned short u16;

constexpr int cLP = 400, cLQ = 50, cB = 32, cH = 150, cG = 600;

__device__ __forceinline__ float exp2_(float x){
#if __has_builtin(__builtin_amdgcn_exp2f)
  return __builtin_amdgcn_exp2f(x);
#else
  return exp2f(x);
#endif
}
__device__ __forceinline__ float rcp_(float x){
#if __has_builtin(__builtin_amdgcn_rcpf)
  return __builtin_amdgcn_rcpf(x);
#else
  return 1.0f / x;
#endif
}
__device__ __forceinline__ float sigm(float x){ return rcp_(1.f + exp2_(-1.44269504f * x)); }
__device__ __forceinline__ float tanh_(float x){ return 1.f - 2.f * rcp_(1.f + exp2_(2.88539008f * x)); }

union U2 { u32 u; f16x2 h; };

__device__ __forceinline__ float fdot2_(u32 a, u32 b, float c){
  U2 ua, ub; ua.u = a; ub.u = b;
#if __has_builtin(__builtin_amdgcn_fdot2)
  return __builtin_amdgcn_fdot2(ua.h, ub.h, c, false);
#else
  return c + (float)ua.h[0] * (float)ub.h[0] + (float)ua.h[1] * (float)ub.h[1];
#endif
}
__device__ __forceinline__ u32 pack2(float x, float y){
  U2 p; p.h[0] = (f16)x; p.h[1] = (f16)y; return p.u;
}
__device__ __forceinline__ float2 unp2(u32 v){
  U2 p; p.u = v; return make_float2((float)p.h[0], (float)p.h[1]);
}

// load 4 f16x2 pairs (8 floats) from a weight row at float offset 8*i
__device__ __forceinline__ uint4 ldw4(const float* __restrict__ wr, int i){
  uint4 r;
  r.x = pack2(wr[8*i+0], wr[8*i+1]);
  r.y = pack2(wr[8*i+2], wr[8*i+3]);
  r.z = pack2(wr[8*i+4], wr[8*i+5]);
  r.w = pack2(wr[8*i+6], wr[8*i+7]);
  return r;
}

// opaque barrier: values become asm outputs -> cannot be rematerialized
#define PIN4(v) asm volatile("" : "+v"(v.x), "+v"(v.y), "+v"(v.z), "+v"(v.w));
#define PIN4W(i) PIN4(w##i)
#define PIN4Q(i) PIN4(q##i)

#define REP10(M) M(0) M(1) M(2) M(3) M(4) M(5) M(6) M(7) M(8) M(9)
#define REP6(M) M(0) M(1) M(2) M(3) M(4) M(5)

// ---------------------------------------------------------------------------
// f16-fdot2 GEMM: C[M][N] = A[M][K] @ W[N][K]^T (+bias, f32). A/W staged as
// f16x2 pairs in LDS; inner loop = 8 packed-k iters x 16 fdot2 per thread.
// Tile 64x64, 4x4/thread, 256 threads. Optional embedding gather, f16 out.
// ---------------------------------------------------------------------------
__global__ __launch_bounds__(256)
void gemm_k(const float* __restrict__ A, const int* __restrict__ ids,
            const float* __restrict__ emb,
            const float* __restrict__ W, int ldw, const float* __restrict__ bias,
            float* __restrict__ Cf, f16* __restrict__ Ch,
            int M, int N, int K)
{
  __shared__ __align__(16) u32 As2[8][64];
  __shared__ __align__(16) u32 Wt2[8][64];
  __shared__ int sids[64];
  int tid = threadIdx.x;
  int n0 = blockIdx.x * 64;
  int m0 = blockIdx.y * 64;
  int tx = tid & 15, ty = tid >> 4;
  if (ids){ if (tid < 64) sids[tid] = ids[m0 + tid]; }
  __syncthreads();

  float acc[4][4] = {};
  int sm = tid >> 2;           // tile row 0..63
  int kq = tid & 3;            // k-quarter: 4 floats = 2 pairs
  const float* arow = ids ? (emb + (size_t)sids[sm] * K)
                          : (A   + (size_t)(m0 + sm) * K);
  const float* wrow = W + (size_t)(n0 + sm) * ldw;
  bool nok = (n0 + sm) < N;

  for (int k0 = 0; k0 < K; k0 += 16){
    {
      int kb = k0 + 4 * kq;
      float a0 = (kb     < K) ? arow[kb]     : 0.f;
      float a1 = (kb + 1 < K) ? arow[kb + 1] : 0.f;
      float a2 = (kb + 2 < K) ? arow[kb + 2] : 0.f;
      float a3 = (kb + 3 < K) ? arow[kb + 3] : 0.f;
      As2[2 * kq][sm]     = pack2(a0, a1);
      As2[2 * kq + 1][sm] = pack2(a2, a3);
      float w0 = (nok && kb     < K) ? wrow[kb]     : 0.f;
      float w1 = (nok && kb + 1 < K) ? wrow[kb + 1] : 0.f;
      float w2 = (nok && kb + 2 < K) ? wrow[kb + 2] : 0.f;
      float w3 = (nok && kb + 3 < K) ? wrow[kb + 3] : 0.f;
      Wt2[2 * kq][sm]     = pack2(w0, w1);
      Wt2[2 * kq + 1][sm] = pack2(w2, w3);
    }
    __syncthreads();
    #pragma unroll
    for (int p = 0; p < 8; p++){
      uint4 av = *(const uint4*)&As2[p][ty << 2];   // broadcast within row-group
      uint4 wv = *(const uint4*)&Wt2[p][tx << 2];
      u32 a[4] = {av.x, av.y, av.z, av.w};
      u32 w[4] = {wv.x, wv.y, wv.z, wv.w};
      #pragma unroll
      for (int i = 0; i < 4; i++)
        #pragma unroll
        for (int j = 0; j < 4; j++)
          acc[i][j] = fdot2_(a[i], w[j], acc[i][j]);
    }
    __syncthreads();
  }
  float bj[4];
  #pragma unroll
  for (int j = 0; j < 4; j++){
    int n = n0 + (tx << 2) + j;
    bj[j] = (bias && n < N) ? bias[n] : 0.f;
  }
  #pragma unroll
  for (int i = 0; i < 4; i++){
    int m = m0 + (ty << 2) + i;
    #pragma unroll
    for (int j = 0; j < 4; j++){
      int n = n0 + (tx << 2) + j;
      if (n < N){
        size_t ci = (size_t)m * N + n;
        float v = acc[i][j] + bj[j];
        if (Ch) Ch[ci] = (f16)v; else Cf[ci] = v;
      }
    }
  }
}

// ---------------------------------------------------------------------------
// Encoder LSTM (R11 structure): Whh pairs 0..39 in 10 pinned uint4 regs,
// pairs 40..75 in LDS uint4 [9][600]; cell on 75 threads; 2 barriers/step.
// ---------------------------------------------------------------------------
__attribute__((amdgpu_waves_per_eu(1, 3)))
__global__ __launch_bounds__(640)
void enc_k(const float* __restrict__ XGp, const float* __restrict__ XGq,
           const float* __restrict__ Whh,
           const int* __restrict__ plens, const int* __restrict__ qlens,
           float* __restrict__ Hp, float* __restrict__ Hq)
{
  int wg = blockIdx.x;
  bool isq = wg >= cB;
  int b = wg & (cB - 1);
  const float* XG = isq ? XGq : XGp;
  float* Hout = isq ? Hq : Hp;
  int T   = isq ? cLQ : cLP;
  int len = (isq ? qlens : plens)[b];
  int tid = threadIdx.x;

  __shared__ __align__(16) u32 WhhL4[9 * 600 * 4];
  __shared__ float c[cH], gl[cG];
  __shared__ __align__(16) u32 h2s[80];

#define DECLW(i) uint4 w##i;
  REP10(DECLW)
#undef DECLW
  {
    const float* wr = Whh + (size_t)(tid < cG ? tid : 0) * cH;
#define LOADW(i) w##i = ldw4(wr, i);
    REP10(LOADW)
#undef LOADW
    REP10(PIN4W)
  }
  for (int idx = tid; idx < 9 * 600; idx += 640){
    int p4 = idx / 600, r = idx % 600;
    const float* wrow = Whh + (size_t)r * cH + 80;
    uint4 v;
    if (p4 < 8) v = ldw4(wrow, p4);
    else {
      v.x = pack2(wrow[64], wrow[65]);
      v.y = pack2(wrow[66], wrow[67]);
      v.z = pack2(wrow[68], wrow[69]);
      v.w = 0;
    }
    *(uint4*)&WhhL4[idx * 4] = v;
  }
  if (tid < cH) c[tid] = 0.f;
  if (tid < 80) h2s[tid] = 0;
  __syncthreads();

  float xgCur = 0.f;
  if (tid < cG) xgCur = XG[(size_t)b * cG + tid];

  for (int t = 0; t < T; t++){
    int tn = (t + 1 < T) ? t + 1 : t;
    float xgN = 0.f;
    if (tid < cG) xgN = XG[((size_t)tn * cB + b) * cG + tid];

    if (tid < cG){
      float aA = 0.f, aB = 0.f, aC = 0.f, aD = 0.f;
#define DOTW(i) { uint4 hq = *(const uint4*)&h2s[4*(i)]; \
      aA = fdot2_(hq.x, w##i.x, aA); aB = fdot2_(hq.y, w##i.y, aB); \
      aC = fdot2_(hq.z, w##i.z, aC); aD = fdot2_(hq.w, w##i.w, aD); }
      REP10(DOTW)
#undef DOTW
      #pragma unroll
      for (int p4 = 0; p4 < 9; p4++){
        uint4 hq = *(const uint4*)&h2s[40 + 4 * p4];
        uint4 wv = *(const uint4*)&WhhL4[(p4 * 600 + tid) * 4];
        aA = fdot2_(hq.x, wv.x, aA);
        aB = fdot2_(hq.y, wv.y, aB);
        aC = fdot2_(hq.z, wv.z, aC);
        aD = fdot2_(hq.w, wv.w, aD);
      }
      gl[tid] = xgCur + ((aA + aB) + (aC + aD));
    }
    __syncthreads();
    if (tid < 75){
      float hv[2];
      #pragma unroll
      for (int z = 0; z < 2; z++){
        int u = 2 * tid + z;
        float ig = sigm(gl[u]);
        float fg = sigm(gl[cH + u]);
        float gg = tanh_(gl[2 * cH + u]);
        float og = sigm(gl[3 * cH + u]);
        float c2 = fg * c[u] + ig * gg;
        float hh = og * tanh_(c2);
        c[u] = c2;
        hv[z] = hh;
      }
      h2s[tid] = pack2(hv[0], hv[1]);      // unmasked h carries the recurrence
      float mk = (t < len) ? 1.f : 0.f;
      float2 st; st.x = hv[0] * mk; st.y = hv[1] * mk;
      *(float2*)&Hout[((size_t)t * cB + b) * cH + 2 * tid] = st;
    }
    __syncthreads();
    xgCur = xgN;
  }
}

// ---------------------------------------------------------------------------
// Match-LSTM, fwd + bwd (R12/R14 structure). 64 WGs = dir(2) x batch(32),
// 640 threads. P_A: sc 4-lane split. P_B: gates_pre (VGPR) + logits fused.
// P_C: softmax. P_D: alpha-dots + gl write. P_E: cell on 150 thr.
// ---------------------------------------------------------------------------
__attribute__((amdgpu_waves_per_eu(1, 3)))
__global__ __launch_bounds__(640)
void match_k(const f16* __restrict__ XAf, const f16* __restrict__ XAb,
             const f16* __restrict__ QWf, const f16* __restrict__ QWb,
             const float* __restrict__ aq, const float* __restrict__ pp,
             const float* __restrict__ mfWhh, const float* __restrict__ mbWhh,
             const float* __restrict__ mfb, const float* __restrict__ mbb,
             const float* __restrict__ Wr, const float* __restrict__ wa,
             const int* __restrict__ plens, float* __restrict__ Hr)
{
  constexpr int NPAD = 160;
  int wg = blockIdx.x;
  int dir = wg >> 5;
  int b = wg & 31;
  const f16* XA = dir ? XAb : XAf;
  const f16* QW = dir ? QWb : QWf;
  const float* Whh = dir ? mbWhh : mfWhh;
  const float* bm  = dir ? mbb   : mfb;
  int len = plens[b];
  int tid = threadIdx.x;

  __shared__ __align__(16) u32 WhhL4[9 * 600 * 4];   // 86.4 KB
  __shared__ __align__(16) u32 WrT4[20 * 150 * 4];   // 48 KB (row 19 = zeros)
  __shared__ __align__(16) u32 aq3[cLQ * 96];        // 19.2 KB
  __shared__ float gl[cG];
  __shared__ __align__(16) float sc[NPAD];
  __shared__ __align__(16) float waS[NPAD];
  __shared__ float c[cH];
  __shared__ __align__(16) f16 hsf[160];             // h as raw f16
  __shared__ float loge[64];
  __shared__ __align__(16) u32 alpha2[28];

  // ---- one-time loads ----
#define DECLW(i) uint4 w##i;
  REP10(DECLW)
#undef DECLW
  float bk = 0.f;
  {
    const float* wr = Whh + (size_t)(tid < cG ? tid : 0) * cH;
#define LOADW(i) w##i = ldw4(wr, i);
    REP10(LOADW)
#undef LOADW
    REP10(PIN4W)
    if (tid < cG) bk = bm[tid];
  }
#define DECLQ(i) uint4 q##i;
  REP6(DECLQ)
#undef DECLQ
  u32 q24s;
  {
    const u16* QWu = (const u16*)QW;
    int row = (tid < cG) ? tid : 0;
#define QP(p) ((u32)QWu[((size_t)(2*(p)) * cB + b) * cG + row] | \
               ((u32)QWu[((size_t)(2*(p)+1) * cB + b) * cG + row] << 16))
#define LOADQ(i) q##i.x = QP(4*(i)+0); q##i.y = QP(4*(i)+1); \
                 q##i.z = QP(4*(i)+2); q##i.w = QP(4*(i)+3);
    LOADQ(0) LOADQ(1) LOADQ(2) LOADQ(3) LOADQ(4) LOADQ(5)
    q24s = QP(24);
#undef LOADQ
#undef QP
    REP6(PIN4Q)
    asm volatile("" : "+v"(q24s));
  }
  for (int idx = tid; idx < 9 * 600; idx += 640){
    int p4 = idx / 600, r = idx % 600;
    const float* wrow = Whh + (size_t)r * cH + 80;
    uint4 v;
    if (p4 < 8) v = ldw4(wrow, p4);
    else {
      v.x = pack2(wrow[64], wrow[65]);
      v.y = pack2(wrow[66], wrow[67]);
      v.z = pack2(wrow[68], wrow[69]);
      v.w = 0;
    }
    *(uint4*)&WhhL4[idx * 4] = v;
  }
  for (int idx = tid; idx < 20 * 150; idx += 640){
    int i = idx / 150, j = idx % 150;
    const float* wrow = Wr + (size_t)j * cH;
    uint4 v = {0, 0, 0, 0};
    if (i < 18) v = ldw4(wrow, i);
    else if (i == 18){
      v.x = pack2(wrow[144], wrow[145]);
      v.y = pack2(wrow[146], wrow[147]);
      v.z = pack2(wrow[148], wrow[149]);
      v.w = 0;
    }
    *(uint4*)&WrT4[idx * 4] = v;
  }
  for (int idx = tid; idx < cLQ * 96; idx += 640){
    int l = idx / 96, s = idx % 96;
    int ch = s / 12, t = s % 12;
    u32 v = 0;
    if (t < 10){
      int p = ch * 10 + t;
      if (p < 75){
        const float* ap = aq + ((size_t)l * cB + b) * cH;
        v = pack2(ap[2 * p], ap[2 * p + 1]);
      }
    }
    aq3[idx] = v;
  }
  for (int i = tid; i < NPAD; i += 640) waS[i] = (i < cH) ? wa[i] : 0.f;
  if (tid < cH) c[tid] = 0.f;
  if (tid < 160) hsf[tid] = (f16)0.f;
  if (tid >= cH && tid < NPAD) sc[tid] = 0.f;
  if (tid >= 25 && tid < 28) alpha2[tid] = 0;
  __syncthreads();

  // prologue prefetch for step 0
  f16 xaCurH = (f16)0.f, xaNxtH = (f16)0.f;
  float ppCur = 0.f, ppNxt = 0.f;
  {
    int t0 = dir ? (cLP - 1) : 0;
    if (tid < cG) xaCurH = XA[((size_t)t0 * cB + b) * cG + tid];
    if (tid < cG && (tid & 3) == 0)
      ppCur = pp[((size_t)t0 * cB + b) * cH + (tid >> 2)];
  }

  for (int s = 0; s < cLP; s++){
    int tt = dir ? (cLP - 1 - s) : s;
    float mk = (tt < len) ? 1.f : 0.f;

    // prefetch step s+1 (consumed next iteration)
    {
      int sn = (s + 1 < cLP) ? s + 1 : s;
      int tn = dir ? (cLP - 1 - sn) : sn;
      if (tid < cG) xaNxtH = XA[((size_t)tn * cB + b) * cG + tid];
      if (tid < cG && (tid & 3) == 0)
        ppNxt = pp[((size_t)tn * cB + b) * cH + (tid >> 2)];
    }

    // P_A: sc = h@Wr^T + pp[tt]; 4 lanes per column, shfl reduce.
    if (tid < cG){
      int q = tid & 3, j = tid >> 2;
      float sA = 0.f, sB = 0.f, sC = 0.f, sD = 0.f;
      #pragma unroll
      for (int i0 = 0; i0 < 5; i0++){
        int i = 5 * q + i0;               // q=3,i0=4 -> row 19 (zeros)
        uint4 hq = *(const uint4*)&hsf[8 * i];
        uint4 wv = *(const uint4*)&WrT4[(i * 150 + j) * 4];
        sA = fdot2_(hq.x, wv.x, sA);
        sB = fdot2_(hq.y, wv.y, sB);
        sC = fdot2_(hq.z, wv.z, sC);
        sD = fdot2_(hq.w, wv.w, sD);
      }
      float v = (sA + sB) + (sC + sD);
      v += __shfl_xor(v, 1);
      v += __shfl_xor(v, 2);
      if (q == 0) sc[j] = v + ppCur;
    }
    __syncthreads();

    // P_B: gates_pre (tid<600, WhhL4 stream, kept in VGPR) + logits (tid<400)
    float gpre = 0.f;
    if (tid < cG){
      float aA = 0.f, aB = 0.f, aC = 0.f, aD = 0.f;
#define DOTW(i) { uint4 hq = *(const uint4*)&hsf[8*(i)]; \
      aA = fdot2_(hq.x, w##i.x, aA); aB = fdot2_(hq.y, w##i.y, aB); \
      aC = fdot2_(hq.z, w##i.z, aC); aD = fdot2_(hq.w, w##i.w, aD); }
      REP10(DOTW)
#undef DOTW
      #pragma unroll
      for (int p4 = 0; p4 < 9; p4++){
        uint4 hq = *(const uint4*)&hsf[80 + 8 * p4];
        uint4 wv = *(const uint4*)&WhhL4[(p4 * 600 + tid) * 4];
        aA = fdot2_(hq.x, wv.x, aA);
        aB = fdot2_(hq.y, wv.y, aB);
        aC = fdot2_(hq.z, wv.z, aC);
        aD = fdot2_(hq.w, wv.w, aD);
      }
      gpre = bk + ((aA + aB) + (aC + aD));
    }
    if (tid < 400){
      int l = tid >> 3, q8 = tid & 7;
      const u32* ab = aq3 + l * 96 + q8 * 12;
      uint4 A0 = *(const uint4*)(ab);
      uint4 A1 = *(const uint4*)(ab + 4);
      uint2 A2 = *(const uint2*)(ab + 8);
      u32 aqp[10] = {A0.x, A0.y, A0.z, A0.w, A1.x, A1.y, A1.z, A1.w, A2.x, A2.y};
      const float4* scv = (const float4*)(sc  + 20 * q8);
      const float4* wav = (const float4*)(waS + 20 * q8);
      float p0 = 0.f, p1 = 0.f;
      #pragma unroll
      for (int i = 0; i < 5; i++){
        float4 sv = scv[i];
        float4 wv = wav[i];
        float2 a0 = unp2(aqp[2 * i]);
        float2 a1 = unp2(aqp[2 * i + 1]);
        p0 += wv.x * rcp_(1.f + exp2_(2.88539008f * (a0.x + sv.x)));
        p1 += wv.y * rcp_(1.f + exp2_(2.88539008f * (a0.y + sv.y)));
        p0 += wv.z * rcp_(1.f + exp2_(2.88539008f * (a1.x + sv.z)));
        p1 += wv.w * rcp_(1.f + exp2_(2.88539008f * (a1.y + sv.w)));
      }
      float part = p0 + p1;
      part += __shfl_xor(part, 1);
      part += __shfl_xor(part, 2);
      part += __shfl_xor(part, 4);
      if (q8 == 0) loge[l] = part;
    }
    __syncthreads();

    // P_C: softmax over 50 on wave 0, f16-packed alpha pairs
    if (tid < 64){
      float lg = (tid < cLQ) ? (-2.f * loge[tid]) : -1e30f;
      float mx = lg;
      #pragma unroll
      for (int off = 32; off; off >>= 1) mx = fmaxf(mx, __shfl_xor(mx, off));
      float e = (tid < cLQ) ? exp2_((lg - mx) * 1.44269504f) : 0.f;
      float sum = e;
      #pragma unroll
      for (int off = 32; off; off >>= 1) sum += __shfl_xor(sum, off);
      float al = e * rcp_(sum);
      float alhi = __shfl_down(al, 1);
      if (tid < cLQ && !(tid & 1)) alpha2[tid >> 1] = pack2(al, alhi);
    }
    __syncthreads();

    // P_D: gl = gpre + mk*(XA + alpha@QW)
    if (tid < cG){
      float qA = 0.f, qB = 0.f;
#define DOTQ(i) { uint4 a4 = *(const uint4*)&alpha2[4*(i)]; \
      qA = fdot2_(a4.x, q##i.x, qA); qB = fdot2_(a4.y, q##i.y, qB); \
      qA = fdot2_(a4.z, q##i.z, qA); qB = fdot2_(a4.w, q##i.w, qB); }
      REP6(DOTQ)
#undef DOTQ
      qA = fdot2_(alpha2[24], q24s, qA);
      gl[tid] = gpre + mk * ((float)xaCurH + (qA + qB));
    }
    __syncthreads();

    // P_E: cell on 150 threads; h2,c2 masked inside recurrence.
    if (tid < cH){
      float ig = sigm(gl[tid]);
      float fg = sigm(gl[cH + tid]);
      float gg = tanh_(gl[2 * cH + tid]);
      float og = sigm(gl[3 * cH + tid]);
      float c2 = (fg * c[tid] + ig * gg) * mk;
      float hh = og * tanh_(c2) * mk;
      c[tid] = c2;
      hsf[tid] = (f16)hh;
      Hr[((size_t)tt * cB + b) * (2 * cH) + dir * cH + tid] = hh;
    }
    __syncthreads();

    xaCurH = xaNxtH;
    ppCur  = ppNxt;
  }
}

// ---------------------------------------------------------------------------
// Answer pointer: 32 WGs (one per batch), 2 sequential iterations.
// ---------------------------------------------------------------------------
__global__ __launch_bounds__(640)
void ptr_k(const float* __restrict__ am, const float* __restrict__ Hr,
           const float* __restrict__ Wa, const float* __restrict__ baa,
           const float* __restrict__ wb,
           const float* __restrict__ apWih, const float* __restrict__ apWhh,
             const float* __restrict__ apb, float* __restrict__ out)
{
  int b = blockIdx.x, tid = threadIdx.x;
  __shared__ float ha[cH], ca[cH], haWa[160], wbs[160];
  __shared__ float beta[cLP], wHr[2 * cH], gl[cG], red[20];
  if (tid < cH){ ha[tid] = 0.f; ca[tid] = 0.f; }
  if (tid < 160) wbs[tid] = (tid < cH) ? wb[tid] : 0.f;
  __syncthreads();

  for (int it = 0; it < 2; ++it){
    if (tid < cH){
      float acc = baa[tid];
      const float* wr = Wa + (size_t)tid * cH;
      for (int i = 0; i < cH; i++) acc += ha[i] * wr[i];
      haWa[tid] = acc;
    } else if (tid < 160) haWa[tid] = 0.f;
    __syncthreads();

    {
      int tt = tid >> 4;
      int jq = tid & 15;
      for (int t0 = 0; t0 < cLP; t0 += 40){
        int t = t0 + tt;
        float part = 0.f;
        const float* amr = am + ((size_t)t * cB + b) * cH;
        #pragma unroll
        for (int i = 0; i < 10; i++){
          int j = jq * 10 + i;
          if (j < cH){
            float F = tanh_(amr[j] + haWa[j]);
            part += wbs[j] * F;
          }
        }
        part += __shfl_xor(part, 1);
        part += __shfl_xor(part, 2);
        part += __shfl_xor(part, 4);
        part += __shfl_xor(part, 8);
        if (jq == 0) beta[t] = part;
      }
    }
    __syncthreads();

    float x = (tid < cLP) ? beta[tid] : -1e30f;
    float mx = x;
    #pragma unroll
    for (int off = 32; off; off >>= 1) mx = fmaxf(mx, __shfl_xor(mx, off));
    if ((tid & 63) == 0) red[tid >> 6] = mx;
    __syncthreads();
    if (tid == 0){
      float m2 = red[0];
      for (int w = 1; w < 10; w++) m2 = fmaxf(m2, red[w]);
      red[16] = m2;
    }
    __syncthreads();
    mx = red[16];
    float e = (tid < cLP) ? exp2_((x - mx) * 1.44269504f) : 0.f;
    float sm = e;
    #pragma unroll
    for (int off = 32; off; off >>= 1) sm += __shfl_xor(sm, off);
    if ((tid & 63) == 0) red[tid >> 6] = sm;
    __syncthreads();
    if (tid == 0){
      float s2 = 0.f;
      for (int w = 0; w < 10; w++) s2 += red[w];
      red[17] = s2;
    }
    __syncthreads();
    float bsum = red[17];
    if (tid < cLP){
      float bt = e * rcp_(bsum);
      beta[tid] = bt;
      out[(size_t)it * cLP * cB + (size_t)tid * cB + b] = bt;
    }
    __syncthreads();

    if (tid < 2 * cH){
      float acc = 0.f;
      for (int t = 0; t < cLP; t++)
        acc += beta[t] * Hr[((size_t)t * cB + b) * (2 * cH) + tid];
      wHr[tid] = acc;
    }
    __syncthreads();

    if (tid < cG){
      float acc = apb[tid];
      const float* r1 = apWih + (size_t)tid * (2 * cH);
      for (int i = 0; i < 2 * cH; i++) acc += wHr[i] * r1[i];
      const float* r2 = apWhh + (size_t)tid * cH;
      for (int i = 0; i < cH; i++) acc += ha[i] * r2[i];
      gl[tid] = acc;
    }
    __syncthreads();
    if (tid < cH){
      float ig = sigm(gl[tid]);
      float fg = sigm(gl[cH + tid]);
      float gg = tanh_(gl[2 * cH + tid]);
      float og = sigm(gl[3 * cH + tid]);
      float c2 = fg * ca[tid] + ig * gg;
      ca[tid] = c2;
      ha[tid] = og * tanh_(c2);
    }
    __syncthreads();
  }
}

// ---------------------------------------------------------------------------
extern "C" void kernel_launch(void* const* d_in, const int* in_sizes, int n_in,
                              void* d_out, int out_size, void* d_ws, size_t ws_size,
                              hipStream_t stream)
{
  (void)in_sizes; (void)n_in; (void)out_size; (void)ws_size;
  const int*   p_ids = (const int*)d_in[0];
  const int*   q_ids = (const int*)d_in[1];
  const int*   plens = (const int*)d_in[2];
  const int*   qlens = (const int*)d_in[3];
  const float* emb   = (const float*)d_in[4];
  const float* pWih  = (const float*)d_in[5];
  const float* pWhh  = (const float*)d_in[6];
  const float* pb    = (const float*)d_in[7];
  const float* Wq    = (const float*)d_in[8];
  const float* Wp    = (const float*)d_in[9];
  const float* bp    = (const float*)d_in[10];
  const float* Wr    = (const float*)d_in[11];
  const float* wa    = (const float*)d_in[12];
  const float* mfWih = (const float*)d_in[14];
  const float* mfWhh = (const float*)d_in[15];
  const float* mfb   = (const float*)d_in[16];
  const float* mbWih = (const float*)d_in[17];
  const float* mbWhh = (const float*)d_in[18];
  const float* mbb   = (const float*)d_in[19];
  const float* Vm    = (const float*)d_in[20];
  const float* Waa   = (const float*)d_in[21];
  const float* baa   = (const float*)d_in[22];
  const float* wb    = (const float*)d_in[23];
  const float* apWih = (const float*)d_in[25];
  const float* apWhh = (const float*)d_in[26];
  const float* apb   = (const float*)d_in[27];
  float* out = (float*)d_out;

  // workspace layout (floats); total 22,560,000 f = 90.24 MB
  float* ws  = (float*)d_ws;
  float* XGp = ws;                       // [400*32][600] f32 (later aliased XAf)
  float* XGq = ws + 7680000;             // [50*32][600]  f32 (later aliased QW)
  f16*   XAb = (f16*)(ws + 8640000);     // [400*32][600] f16
  float* Hp  = ws + 12480000;            // [400*32][150]
  float* Hq  = ws + 14400000;            // [50*32][150]
  float* aqb = ws + 14640000;            // [50*32][150]
  float* ppb = ws + 14880000;            // [400*32][150]
  float* Hr  = ws + 16800000;            // [400*32][300]
  float* am  = ws + 20640000;            // [400*32][150]
  f16*   XAf = (f16*)XGp;                // alias: XGp dead after enc_k
  f16*   QWf = (f16*)XGq;                // alias: XGq dead after enc_k
  f16*   QWb = QWf + (size_t)1600 * 600;

  dim3 blk(256);
  gemm_k<<<dim3(10,200), blk, 0, stream>>>(nullptr, p_ids, emb, pWih, 300, pb,
                                           XGp, nullptr, 12800, 600, 300);
  gemm_k<<<dim3(10, 25), blk, 0, stream>>>(nullptr, q_ids, emb, pWih, 300, pb,
                                           XGq, nullptr, 1600, 600, 300);
  enc_k<<<64, 640, 0, stream>>>(XGp, XGq, pWhh, plens, qlens, Hp, Hq);
  gemm_k<<<dim3(3,200), blk, 0, stream>>>(Hp, nullptr, nullptr, Wp, 150, bp,
                                          ppb, nullptr, 12800, 150, 150);
  gemm_k<<<dim3(3, 25), blk, 0, stream>>>(Hq, nullptr, nullptr, Wq, 150, nullptr,
                                          aqb, nullptr, 1600, 150, 150);
  gemm_k<<<dim3(10,200), blk, 0, stream>>>(Hp, nullptr, nullptr, mfWih, 300, nullptr,
                                           nullptr, XAf, 12800, 600, 150);
  gemm_k<<<dim3(10,200), blk, 0, stream>>>(Hp, nullptr, nullptr, mbWih, 300, nullptr,
                                           nullptr, XAb, 12800, 600, 150);
  gemm_k<<<dim3(10, 25), blk, 0, stream>>>(Hq, nullptr, nullptr, mfWih + 150, 300, nullptr,
                                           nullptr, QWf, 1600, 600, 150);
  gemm_k<<<dim3(10, 25), blk, 0, stream>>>(Hq, nullptr, nullptr, mbWih + 150, 300, nullptr,
                                           nullptr, QWb, 1600, 600, 150);
  match_k<<<64, 640, 0, stream>>>(XAf, XAb, QWf, QWb, aqb, ppb, mfWhh, mbWhh,
                                  mfb, mbb, Wr, wa, plens, Hr);
  gemm_k<<<dim3(3,200), blk, 0, stream>>>(Hr, nullptr, nullptr, Vm, 300, nullptr,
                                          am, nullptr, 12800, 150, 300);
  ptr_k<<<32, 640, 0, stream>>>(am, Hr, Waa, baa, wb, apWih, apWhh, apb, out);
}